// Round 2
// baseline (181.117 us; speedup 1.0000x reference)
//
#include <hip/hip_runtime.h>
#include <stdint.h>

#define NCAT  919
#define KDIM  400
#define NDIM  100
#define BK    32
#define NSTEP 13                 // ceil(400/32); step 12 has 16 valid k
#define NPAD  112                // 7*16 padded N
#define LROW  40                 // padded LDS row (bf16 elems): 80B, keeps b128 alignment
#define WBUF  (NPAD * LROW)      // 4480 elems = 8.96 KB; 3 buffers = 26.9 KB

typedef float  f32x4  __attribute__((ext_vector_type(4)));
typedef __bf16 bf16x8 __attribute__((ext_vector_type(8)));
typedef __bf16 bf16x2 __attribute__((ext_vector_type(2)));

__global__ void __launch_bounds__(512, 4)
cat_dense(const float* __restrict__ in, const float* __restrict__ wt,
          const float* __restrict__ bias, float* __restrict__ out)
{
  __shared__ __bf16 wlds[3 * WBUF];

  const int c    = blockIdx.x;
  const int tid  = threadIdx.x;
  const int lane = tid & 63;
  const int wave = tid >> 6;

  // ---- W staging geometry: threads 0..399 transpose W[k][n] -> Wt[n][k] ----
  const bool w_act = tid < 400;
  const int  w_kp  = tid / 25;                   // k-pair index 0..15
  const int  w_nq  = (tid - w_kp * 25) * 4;      // n quad 0..96
  const float* gW  = wt + (size_t)c * (KDIM * NDIM);

  // ---- A: direct global->reg in MFMA fragment layout (rows private per wave) ----
  const int rl = lane & 15;                      // fragment row
  const int kg = (lane >> 4) * 8;                // fragment k offset
  const size_t rstride = (size_t)NCAT * KDIM;    // stride between batch rows
  const float* gA0 = in + (size_t)c * KDIM + (size_t)(wave * 32 + rl) * rstride;
  const float* gA1 = gA0 + (size_t)16 * rstride;

  f32x4 wreg[2][2];       // 2 prefetch slots x {k0-row, k0+1-row}
  f32x4 areg[2][2][2];    // [pingpong][m-tile][16B half]
  f32x4 acc[2][7];
  #pragma unroll
  for (int m = 0; m < 2; ++m)
    #pragma unroll
    for (int n = 0; n < 7; ++n) acc[m][n] = f32x4{0.f, 0.f, 0.f, 0.f};

#define LOADW(T, S) do {                                                  \
    const int k0_ = (T) * BK + 2 * w_kp;                                  \
    if (w_act && k0_ < KDIM) {                                            \
      const float* p_ = gW + (size_t)k0_ * NDIM + w_nq;                   \
      wreg[S][0] = *(const f32x4*)p_;                                     \
      wreg[S][1] = *(const f32x4*)(p_ + NDIM);                            \
    } else {                                                              \
      wreg[S][0] = f32x4{0.f,0.f,0.f,0.f};                                \
      wreg[S][1] = f32x4{0.f,0.f,0.f,0.f};                                \
    }                                                                     \
  } while (0)

#define WRITEW(S, BUF) do {                                               \
    if (w_act) {                                                          \
      __bf16* Lw_ = &wlds[(BUF) * WBUF];                                  \
      _Pragma("unroll")                                                   \
      for (int j_ = 0; j_ < 4; ++j_) {                                    \
        bf16x2 pk_ = { (__bf16)wreg[S][0][j_], (__bf16)wreg[S][1][j_] };  \
        *(bf16x2*)&Lw_[(w_nq + j_) * LROW + 2 * w_kp] = pk_;              \
      }                                                                   \
    }                                                                     \
  } while (0)

#define LOADA(T, PP) do {                                                 \
    const int kb_ = (T) * BK + kg;                                        \
    if (kb_ < KDIM) {   /* 8-chunks align with K tail (400 = 50*8) */     \
      areg[PP][0][0] = *(const f32x4*)(gA0 + kb_);                        \
      areg[PP][0][1] = *(const f32x4*)(gA0 + kb_ + 4);                    \
      areg[PP][1][0] = *(const f32x4*)(gA1 + kb_);                        \
      areg[PP][1][1] = *(const f32x4*)(gA1 + kb_ + 4);                    \
    } else {                                                              \
      areg[PP][0][0] = f32x4{0.f,0.f,0.f,0.f};                            \
      areg[PP][0][1] = f32x4{0.f,0.f,0.f,0.f};                            \
      areg[PP][1][0] = f32x4{0.f,0.f,0.f,0.f};                            \
      areg[PP][1][1] = f32x4{0.f,0.f,0.f,0.f};                            \
    }                                                                     \
  } while (0)

  // ---- prologue: W(0)->LDS0, W(1)->slot1, A(0)->pp0 ----
  LOADW(0, 0);
  LOADA(0, 0);
  WRITEW(0, 0);
  LOADW(1, 1);
  asm volatile("s_waitcnt lgkmcnt(0)" ::: "memory");
  __builtin_amdgcn_s_barrier();

  // ---- main loop: ONE raw barrier per step, vmcnt stays in flight across it ----
  #pragma unroll
  for (int t = 0; t < NSTEP; ++t) {
    const int buf = t % 3;
    const int pp  = t & 1;
    if (t + 1 < NSTEP) LOADA(t + 1, pp ^ 1);       // A(t+1): retires next iter
    if (t + 2 < NSTEP) LOADW(t + 2, t & 1);        // W(t+2): slot freed last iter
    if (t + 1 < NSTEP) WRITEW((t + 1) & 1, (t + 1) % 3);  // W(t+1) -> next buffer

    bf16x8 a0, a1;
    #pragma unroll
    for (int j = 0; j < 4; ++j) {                  // cvt A(t) (loads retired by W-wait above)
      a0[j]     = (__bf16)areg[pp][0][0][j];
      a0[4 + j] = (__bf16)areg[pp][0][1][j];
      a1[j]     = (__bf16)areg[pp][1][0][j];
      a1[4 + j] = (__bf16)areg[pp][1][1][j];
    }
    const __bf16* Lw = &wlds[buf * WBUF];
    #pragma unroll
    for (int n = 0; n < 7; ++n) {
      bf16x8 b = *(const bf16x8*)&Lw[(n * 16 + rl) * LROW + kg];
      acc[0][n] = __builtin_amdgcn_mfma_f32_16x16x32_bf16(a0, b, acc[0][n], 0, 0, 0);
      acc[1][n] = __builtin_amdgcn_mfma_f32_16x16x32_bf16(a1, b, acc[1][n], 0, 0, 0);
    }
    // triple-buffer => writes to buf (t+1)%3 are 2 barriers ahead of its readers;
    // only LDS must drain here — global prefetch loads stay outstanding.
    asm volatile("s_waitcnt lgkmcnt(0)" ::: "memory");
    __builtin_amdgcn_s_barrier();
  }

  // ---- epilogue: C/D map (16x16): col = lane&15, row = (lane>>4)*4 + reg ----
  const float* gB = bias + (size_t)c * NDIM;
  float* gO = out + (size_t)c * NDIM;
  #pragma unroll
  for (int n = 0; n < 7; ++n) {
    const int col = n * 16 + rl;
    if (col < NDIM) {
      const float bv = gB[col];
      #pragma unroll
      for (int m = 0; m < 2; ++m) {
        const int r0 = wave * 32 + m * 16 + (lane >> 4) * 4;
        #pragma unroll
        for (int j = 0; j < 4; ++j) {
          gO[(size_t)(r0 + j) * (NCAT * NDIM) + col] = acc[m][n][j] + bv;
        }
      }
    }
  }
}

extern "C" void kernel_launch(void* const* d_in, const int* in_sizes, int n_in,
                              void* d_out, int out_size, void* d_ws, size_t ws_size,
                              hipStream_t stream) {
  const float* in   = (const float*)d_in[0];
  const float* wt   = (const float*)d_in[1];
  const float* bias = (const float*)d_in[2];
  float* o          = (float*)d_out;
  cat_dense<<<dim3(NCAT), dim3(512), 0, stream>>>(in, wt, bias, o);
}

// Round 5
// 150.392 us; speedup vs baseline: 1.2043x; 1.2043x over previous
//
#include <hip/hip_runtime.h>
#include <stdint.h>

#define NCAT  919
#define KDIM  400
#define NDIM  100
#define BK    32
#define NSTEP 13                 // ceil(400/32); step 12 has 16 valid k
#define KPAD  408                // LDS row (bf16): 816 B = 204 dwords; start-bank stride
                                 // 12 -> 16 rows x b128 hit all 32 banks 2-way (free, m136)
#define NPADR 112                // 7*16 padded N rows

typedef float  f32x4  __attribute__((ext_vector_type(4)));
typedef __bf16 bf16x8 __attribute__((ext_vector_type(8)));
typedef __bf16 bf16x2 __attribute__((ext_vector_type(2)));
typedef unsigned short u16;
typedef u16 u16x8 __attribute__((ext_vector_type(8)));

__global__ void __launch_bounds__(512, 2)
cat_dense(const float* __restrict__ in, const float* __restrict__ wt,
          const float* __restrict__ bias, float* __restrict__ out)
{
  __shared__ __bf16 wlds[NPADR * KPAD];        // 91392 B -> 1 block/CU (by design)

  // Bijective XCD-aware swizzle (m204): 919 = 7*115 + 114. Consecutive categories
  // share an XCD L2 -> partial 128B output lines merge before writeback.
  const int ob   = blockIdx.x;
  const int xcd  = ob & 7;
  const int bidx = ob >> 3;
  const int c    = (xcd < 7 ? xcd * 115 : 805 + (xcd - 7) * 114) + bidx;

  const int tid  = threadIdx.x;
  const int lane = tid & 63;
  const int wave = tid >> 6;
  const int rl   = lane & 15;                  // fragment row (A) / col (B/D)
  const int kg   = (lane >> 4) * 8;            // fragment k offset

  const size_t rstride = (size_t)NCAT * KDIM;  // batch-row stride in A
  const float* gA0 = in + (size_t)c * KDIM + (size_t)(wave * 32 + rl) * rstride;
  const float* gA1 = gA0 + (size_t)16 * rstride;
  const float* gW  = wt + (size_t)c * (KDIM * NDIM);

  // 4 prefetch slots, distance-3 prefetch: write slot (t+3)&3 != read slot t&3.
  f32x4 areg[4][2][2];

#define LOADA(T) do {                                                      \
    const int kb_ = (T) * BK + kg;                                         \
    const int s_  = (T) & 3;                                               \
    if (kb_ + 8 <= KDIM) {   /* per-lane K-tail mask (step 12, kg>=16) */  \
      areg[s_][0][0] = *(const f32x4*)(gA0 + kb_);                         \
      areg[s_][0][1] = *(const f32x4*)(gA0 + kb_ + 4);                     \
      areg[s_][1][0] = *(const f32x4*)(gA1 + kb_);                         \
      areg[s_][1][1] = *(const f32x4*)(gA1 + kb_ + 4);                     \
    } else {                                                               \
      areg[s_][0][0] = f32x4{0,0,0,0}; areg[s_][0][1] = f32x4{0,0,0,0};    \
      areg[s_][1][0] = f32x4{0,0,0,0}; areg[s_][1][1] = f32x4{0,0,0,0};    \
    }                                                                      \
  } while (0)

  // ---- prologue: A(0..2) issued first; they drain at the single barrier ----
  LOADA(0);
  LOADA(1);
  LOADA(2);

  // Zero rows 100..111 completely (612 u16x8 chunks): no LDS-read address can
  // ever observe uninitialized data, even in never-stored columns.
  {
    const u16x8 z = {0,0,0,0,0,0,0,0};
    u16* zb = (u16*)&wlds[100 * KPAD];
    *(u16x8*)&zb[tid * 8] = z;
    if (tid < 100) *(u16x8*)&zb[(512 + tid) * 8] = z;
  }

  // ---- stage full W_c -> LDS (transposed, bf16), ONCE ----
  // 5000 k-pair chunks: pc = kp*25 + nq; thread handles W[2kp][4nq..+3] + W[2kp+1][...]
  #pragma unroll
  for (int i = 0; i < 10; ++i) {
    const int pc = tid + i * 512;
    if (pc < 5000) {
      const int kp = pc / 25;
      const int nq = pc - kp * 25;
      const int k  = kp * 2;
      const float* p = gW + (size_t)k * NDIM + nq * 4;
      const f32x4 w0 = *(const f32x4*)p;
      const f32x4 w1 = *(const f32x4*)(p + NDIM);
      #pragma unroll
      for (int j = 0; j < 4; ++j) {
        bf16x2 pk = { (__bf16)w0[j], (__bf16)w1[j] };
        *(bf16x2*)&wlds[(nq * 4 + j) * KPAD + k] = pk;   // 4B-aligned (k even)
      }
    }
  }

  // Single full barrier. __syncthreads() has real fence semantics — LDS reads
  // below CANNOT be hoisted above it (round-4 failure mode: raw s_barrier is
  // IntrNoMem, so the compiler could order ds_reads before other waves' writes).
  __syncthreads();

  f32x4 acc[2][7];
  #pragma unroll
  for (int m = 0; m < 2; ++m)
    #pragma unroll
    for (int n = 0; n < 7; ++n) acc[m][n] = f32x4{0, 0, 0, 0};

  // ---- main loop: ZERO barriers; W read-only in LDS; A streams via registers ----
  #pragma unroll
  for (int t = 0; t < NSTEP; ++t) {
    if (t + 3 < NSTEP) LOADA(t + 3);           // writes slot (t+3)&3, disjoint from t&3
    const int pp = t & 3;
    bf16x8 a0, a1;
    #pragma unroll
    for (int j = 0; j < 4; ++j) {              // vmcnt wait for A(t) lands here
      a0[j]     = (__bf16)areg[pp][0][0][j];
      a0[4 + j] = (__bf16)areg[pp][0][1][j];
      a1[j]     = (__bf16)areg[pp][1][0][j];
      a1[4 + j] = (__bf16)areg[pp][1][1][j];
    }
    // Clamp B k-offset to KDIM-8: lanes that clamp (t=12, kg>=16) have A==0, so
    // any finite staged value is correct. No read ever touches k>=400 -> no OOB.
    const int kb2  = t * BK + kg;
    const int koff = (kb2 <= KDIM - 8) ? kb2 : (KDIM - 8);
    #pragma unroll
    for (int n = 0; n < 7; ++n) {
      bf16x8 b = *(const bf16x8*)&wlds[(n * 16 + rl) * KPAD + koff];
      acc[0][n] = __builtin_amdgcn_mfma_f32_16x16x32_bf16(a0, b, acc[0][n], 0, 0, 0);
      acc[1][n] = __builtin_amdgcn_mfma_f32_16x16x32_bf16(a1, b, acc[1][n], 0, 0, 0);
    }
  }

  // ---- epilogue: C/D map (16x16 family): col = lane&15, row = (lane>>4)*4 + reg ----
  const float* gB = bias + (size_t)c * NDIM;
  float* gO = out + (size_t)c * NDIM;
  #pragma unroll
  for (int n = 0; n < 7; ++n) {
    const int col = n * 16 + rl;
    if (col < NDIM) {
      const float bv = gB[col];
      #pragma unroll
      for (int m = 0; m < 2; ++m) {
        const int r0 = wave * 32 + m * 16 + (lane >> 4) * 4;
        #pragma unroll
        for (int j = 0; j < 4; ++j) {
          gO[(size_t)(r0 + j) * (NCAT * NDIM) + col] = acc[m][n][j] + bv;
        }
      }
    }
  }
}

extern "C" void kernel_launch(void* const* d_in, const int* in_sizes, int n_in,
                              void* d_out, int out_size, void* d_ws, size_t ws_size,
                              hipStream_t stream) {
  const float* in   = (const float*)d_in[0];
  const float* wt   = (const float*)d_in[1];
  const float* bias = (const float*)d_in[2];
  float* o          = (float*)d_out;
  cat_dense<<<dim3(NCAT), dim3(512), 0, stream>>>(in, wt, bias, o);
}